// Round 2
// baseline (144.435 us; speedup 1.0000x reference)
//
#include <hip/hip_runtime.h>

#define EMBED 2048
#define HEAD 128
#define BATCH 8
#define SEQ 2048

typedef __attribute__((ext_vector_type(4))) float f32x4;
typedef __attribute__((ext_vector_type(8))) __bf16 bf16x8;
typedef __attribute__((ext_vector_type(8))) short short8;

static __device__ __forceinline__ ushort f2bf(float x){
    unsigned u = __float_as_uint(x);
    u += 0x7fffu + ((u >> 16) & 1u);
    return (ushort)(u >> 16);
}

#define MFMA16(a,b,c) __builtin_amdgcn_mfma_f32_16x16x32_bf16((a),(b),(c),0,0,0)

// ---------------- prep: W [2048][128] f32 -> W^T [3][128][2048] bf16 ----------------
__global__ __launch_bounds__(256) void prep_wt(const float* __restrict__ Wq,
                                               const float* __restrict__ Wk,
                                               const float* __restrict__ Wv,
                                               ushort* __restrict__ wt){
    int n = blockIdx.x;     // 0..127
    int w = blockIdx.y;     // 0..2
    const float* W = (w == 0) ? Wq : ((w == 1) ? Wk : Wv);
    ushort* dst = wt + (size_t)(w * HEAD + n) * EMBED;
    for (int k = threadIdx.x; k < EMBED; k += 256)
        dst[k] = f2bf(W[(size_t)k * HEAD + n]);
}

// ---------------- QKV GEMM: [16384 x 2048] x [2048 x 128] (x3) ----------------
// BM=64, BN=128, BK=64. 4 waves: wave tile 32m x 64n. Grid (3, 256) = 768 blocks.
__global__ __launch_bounds__(256) void qkv_gemm(const float* __restrict__ x,
                                                const ushort* __restrict__ wt,
                                                const float* __restrict__ bq,
                                                const float* __restrict__ bk,
                                                const float* __restrict__ bv,
                                                ushort* __restrict__ Qb,
                                                ushort* __restrict__ Kb,
                                                ushort* __restrict__ Vt){
    __shared__ char smem[33792];           // max(9216+18432, 64*132*4)
    char* xsB  = smem;                     // x tile  [64][72 bf16] (144 B rows)
    char* wslB = smem + 9216;              // w tile [128][72 bf16]
    float* ts  = (float*)smem;             // V transpose buffer [64][132] f32

    const int w     = blockIdx.x;
    const int mtile = blockIdx.y;
    const int tid   = threadIdx.x;
    const int lane  = tid & 63;
    const int wid   = tid >> 6;
    const int l15   = lane & 15, lhi = lane >> 4;
    const int wm    = wid >> 1,  wn  = wid & 1;

    const float* bias = (w == 0) ? bq : ((w == 1) ? bk : bv);
    const ushort* wtw = wt + (size_t)w * HEAD * EMBED;
    const int xrow0 = mtile * 64;

    f32x4 acc[2][4];
    #pragma unroll
    for (int i = 0; i < 2; i++)
        #pragma unroll
        for (int j = 0; j < 4; j++) acc[i][j] = (f32x4){0.f,0.f,0.f,0.f};

    for (int kt = 0; kt < EMBED / 64; ++kt){
        __syncthreads();
        // stage x: 64x64 f32 -> bf16 (1024 float4s, 4/thread)
        #pragma unroll
        for (int j = 0; j < 4; j++){
            int f   = tid + 256 * j;
            int row = f >> 4;
            int c4  = f & 15;
            float4 v = *(const float4*)(x + (size_t)(xrow0 + row) * EMBED + kt * 64 + c4 * 4);
            unsigned p0 = (unsigned)f2bf(v.x) | ((unsigned)f2bf(v.y) << 16);
            unsigned p1 = (unsigned)f2bf(v.z) | ((unsigned)f2bf(v.w) << 16);
            uint2 pk; pk.x = p0; pk.y = p1;
            *(uint2*)(xsB + row * 144 + c4 * 8) = pk;
        }
        // stage wt: 128 rows x 64 k bf16 = 1024 16B-chunks, 4/thread  (BUGFIX: was 2/thread)
        #pragma unroll
        for (int j = 0; j < 4; j++){
            int c   = tid + 256 * j;
            int row = c >> 3;
            int ch  = c & 7;
            short8 v = *(const short8*)(wtw + (size_t)row * EMBED + kt * 64 + ch * 8);
            *(short8*)(wslB + row * 144 + ch * 16) = v;
        }
        __syncthreads();
        #pragma unroll
        for (int kc = 0; kc < 2; kc++){
            bf16x8 af[2], bf[4];
            #pragma unroll
            for (int i = 0; i < 2; i++)
                af[i] = *(const bf16x8*)(xsB + (wm*32 + i*16 + l15) * 144 + kc*64 + lhi*16);
            #pragma unroll
            for (int j = 0; j < 4; j++)
                bf[j] = *(const bf16x8*)(wslB + (wn*64 + j*16 + l15) * 144 + kc*64 + lhi*16);
            #pragma unroll
            for (int i = 0; i < 2; i++)
                #pragma unroll
                for (int j = 0; j < 4; j++)
                    acc[i][j] = MFMA16(af[i], bf[j], acc[i][j]);
        }
    }

    float bvv[4];
    #pragma unroll
    for (int j = 0; j < 4; j++) bvv[j] = bias[wn*64 + j*16 + l15];

    if (w < 2){
        ushort* dst = (w == 0) ? Qb : Kb;
        #pragma unroll
        for (int i = 0; i < 2; i++)
            #pragma unroll
            for (int j = 0; j < 4; j++)
                #pragma unroll
                for (int r = 0; r < 4; r++){
                    int m = mtile*64 + wm*32 + i*16 + lhi*4 + r;
                    int n = wn*64 + j*16 + l15;
                    dst[(size_t)m * HEAD + n] = f2bf(acc[i][j][r] + bvv[j]);
                }
    } else {
        // V: transpose through LDS, write V^T [8][128][2048] bf16 coalesced
        __syncthreads();
        #pragma unroll
        for (int i = 0; i < 2; i++)
            #pragma unroll
            for (int j = 0; j < 4; j++)
                #pragma unroll
                for (int r = 0; r < 4; r++){
                    int ml = wm*32 + i*16 + lhi*4 + r;
                    int n  = wn*64 + j*16 + l15;
                    ts[ml * 132 + n] = acc[i][j][r] + bvv[j];
                }
        __syncthreads();
        int n  = tid >> 1;
        int mc = (tid & 1) * 32;
        int b  = mtile >> 5;                       // 32 mtiles per batch
        int trow = (mtile & 31) * 64 + mc;
        __attribute__((aligned(16))) ushort tmp[32];
        #pragma unroll
        for (int i2 = 0; i2 < 32; i2++) tmp[i2] = f2bf(ts[(mc + i2) * 132 + n]);
        ushort* dst = Vt + ((size_t)(b * HEAD + n)) * SEQ + trow;
        #pragma unroll
        for (int q = 0; q < 4; q++)
            *(short8*)(dst + q * 8) = *(const short8*)(tmp + q * 8);
    }
}

// ---------------- Flash attention, causal ----------------
// Block: 256 thr (4 waves), QBLK=64 (16 rows/wave), KVBLK=64. Grid (32, 8).
__global__ __launch_bounds__(256) void attn(const ushort* __restrict__ Qb,
                                            const ushort* __restrict__ Kb,
                                            const ushort* __restrict__ Vt,
                                            float* __restrict__ out){
    __shared__ char smem[40960];
    char* Ks = smem;            // [64 kv][256 B] chunk-swizzled (^row&15)
    char* Vs = smem + 16384;    // [128 d][128 B] chunk-swizzled (^d&7)
    char* Ps = smem + 32768;    // 4 waves x [16 q][128 B] chunk-swizzled (^q&7)

    const int qtile = blockIdx.x;
    const int b     = blockIdx.y;
    const int qb    = qtile * 64;
    const int tid   = threadIdx.x;
    const int lane  = tid & 63, wid = tid >> 6;
    const int l15   = lane & 15, lhi = lane >> 4;
    const float scale = 0.08838834764831845f;   // 1/sqrt(128)

    // Q fragments (16 rows x 128) hoisted to registers
    bf16x8 qf[4];
    {
        const ushort* qp = Qb + ((size_t)(b * SEQ + qb + wid * 16 + l15)) * HEAD;
        #pragma unroll
        for (int kc = 0; kc < 4; kc++)
            qf[kc] = *(const bf16x8*)(qp + kc * 32 + lhi * 8);
    }

    f32x4 o[8];
    #pragma unroll
    for (int d = 0; d < 8; d++) o[d] = (f32x4){0.f,0.f,0.f,0.f};
    float mr[4] = {-1e30f,-1e30f,-1e30f,-1e30f};
    float lr[4] = {0.f,0.f,0.f,0.f};

    char* Pw = Ps + wid * 2048;

    for (int t = 0; t <= qtile; ++t){
        const int kvb = t * 64;
        __syncthreads();
        // stage K tile [64][128] bf16 (1024 chunks, 4/thread)
        #pragma unroll
        for (int j = 0; j < 4; j++){
            int c = tid + 256 * j;
            int row = c >> 4, ch = c & 15;
            short8 v = *(const short8*)(Kb + ((size_t)(b * SEQ + kvb + row)) * HEAD + ch * 8);
            *(short8*)(Ks + row * 256 + ((ch ^ (row & 15)) * 16)) = v;
        }
        // stage V^T tile [128][64] bf16 (1024 chunks, 4/thread)
        #pragma unroll
        for (int j = 0; j < 4; j++){
            int c = tid + 256 * j;
            int d = c >> 3, ch = c & 7;
            short8 v = *(const short8*)(Vt + ((size_t)(b * HEAD + d)) * SEQ + kvb + ch * 8);
            *(short8*)(Vs + d * 128 + ((ch ^ (d & 7)) * 16)) = v;
        }
        __syncthreads();

        // QK^T : S[16 q][64 kv]
        f32x4 s[4];
        #pragma unroll
        for (int ns = 0; ns < 4; ns++){
            s[ns] = (f32x4){0.f,0.f,0.f,0.f};
            int row = ns * 16 + l15;
            #pragma unroll
            for (int kc = 0; kc < 4; kc++){
                int ch = (kc * 4 + lhi) ^ (row & 15);
                bf16x8 bfr = *(const bf16x8*)(Ks + row * 256 + ch * 16);
                s[ns] = MFMA16(qf[kc], bfr, s[ns]);
            }
        }

        // online softmax
        float mx[4];
        #pragma unroll
        for (int r = 0; r < 4; r++){
            #pragma unroll
            for (int ns = 0; ns < 4; ns++){
                float v = s[ns][r] * scale;
                if (t == qtile){
                    int kvg = kvb + ns * 16 + l15;
                    int qg  = qb + wid * 16 + lhi * 4 + r;
                    if (kvg > qg) v = -1e30f;
                }
                s[ns][r] = v;
            }
            float m0 = fmaxf(fmaxf(s[0][r], s[1][r]), fmaxf(s[2][r], s[3][r]));
            m0 = fmaxf(m0, __shfl_xor(m0, 1));
            m0 = fmaxf(m0, __shfl_xor(m0, 2));
            m0 = fmaxf(m0, __shfl_xor(m0, 4));
            m0 = fmaxf(m0, __shfl_xor(m0, 8));
            mx[r] = m0;
        }
        float alpha[4];
        #pragma unroll
        for (int r = 0; r < 4; r++){
            float mn = fmaxf(mr[r], mx[r]);
            alpha[r] = __expf(mr[r] - mn);
            mr[r] = mn;
            float sum = 0.f;
            #pragma unroll
            for (int ns = 0; ns < 4; ns++){
                float p = __expf(s[ns][r] - mn);
                s[ns][r] = p;
                sum += p;
            }
            sum += __shfl_xor(sum, 1);
            sum += __shfl_xor(sum, 2);
            sum += __shfl_xor(sum, 4);
            sum += __shfl_xor(sum, 8);
            lr[r] = lr[r] * alpha[r] + sum;
        }
        #pragma unroll
        for (int d = 0; d < 8; d++)
            #pragma unroll
            for (int r = 0; r < 4; r++) o[d][r] *= alpha[r];

        // P -> per-wave LDS (swizzled), bf16
        #pragma unroll
        for (int ns = 0; ns < 4; ns++)
            #pragma unroll
            for (int r = 0; r < 4; r++){
                int row = lhi * 4 + r;
                int byteoff = row * 128 + (((ns * 16 + l15) * 2) ^ ((row & 7) << 4));
                *(ushort*)(Pw + byteoff) = f2bf(s[ns][r]);
            }
        asm volatile("s_waitcnt lgkmcnt(0)" ::: "memory");
        __builtin_amdgcn_sched_barrier(0);

        // PV : O += P[16x64] * V[64x128]
        #pragma unroll
        for (int kc = 0; kc < 2; kc++){
            int abyte = l15 * 128 + ((kc * 64 + lhi * 16) ^ ((l15 & 7) << 4));
            bf16x8 af = *(const bf16x8*)(Pw + abyte);
            #pragma unroll
            for (int ds = 0; ds < 8; ds++){
                int drow = ds * 16 + l15;
                int bbyte = drow * 128 + ((kc * 64 + lhi * 16) ^ ((drow & 7) << 4));
                bf16x8 bfr = *(const bf16x8*)(Vs + bbyte);
                o[ds] = MFMA16(af, bfr, o[ds]);
            }
        }
    }

    // epilogue: normalize and store f32
    #pragma unroll
    for (int r = 0; r < 4; r++){
        float inv = 1.0f / lr[r];
        size_t qg = (size_t)(b * SEQ + qb + wid * 16 + lhi * 4 + r);
        #pragma unroll
        for (int ds = 0; ds < 8; ds++)
            out[qg * HEAD + ds * 16 + l15] = o[ds][r] * inv;
    }
}

extern "C" void kernel_launch(void* const* d_in, const int* in_sizes, int n_in,
                              void* d_out, int out_size, void* d_ws, size_t ws_size,
                              hipStream_t stream){
    const float* x  = (const float*)d_in[0];
    const float* Wq = (const float*)d_in[1];
    const float* bq = (const float*)d_in[2];
    const float* Wk = (const float*)d_in[3];
    const float* bk = (const float*)d_in[4];
    const float* Wv = (const float*)d_in[5];
    const float* bv = (const float*)d_in[6];
    float* out = (float*)d_out;

    char* ws = (char*)d_ws;
    ushort* Qb = (ushort*)ws;                                 // 4 MB  [16384][128]
    ushort* Kb = (ushort*)(ws + (size_t)4  * 1024 * 1024);    // 4 MB  [16384][128]
    ushort* Vt = (ushort*)(ws + (size_t)8  * 1024 * 1024);    // 4 MB  [8][128][2048]
    ushort* Wt = (ushort*)(ws + (size_t)12 * 1024 * 1024);    // 1.5 MB [3][128][2048]

    prep_wt <<<dim3(128, 3), 256, 0, stream>>>(Wq, Wk, Wv, Wt);
    qkv_gemm<<<dim3(3, 256), 256, 0, stream>>>(x, Wt, bq, bk, bv, Qb, Kb, Vt);
    attn    <<<dim3(32, 8),  256, 0, stream>>>(Qb, Kb, Vt, out);
}

// Round 4
// 132.351 us; speedup vs baseline: 1.0913x; 1.0913x over previous
//
#include <hip/hip_runtime.h>

#define EMBED 2048
#define HEAD 128
#define BATCH 8
#define SEQ 2048

typedef __attribute__((ext_vector_type(4))) float f32x4;
typedef __attribute__((ext_vector_type(8))) __bf16 bf16x8;
typedef __attribute__((ext_vector_type(8))) short short8;

static __device__ __forceinline__ ushort f2bf(float x){
    unsigned u = __float_as_uint(x);
    u += 0x7fffu + ((u >> 16) & 1u);
    return (ushort)(u >> 16);
}

#define MFMA16(a,b,c) __builtin_amdgcn_mfma_f32_16x16x32_bf16((a),(b),(c),0,0,0)

#define GLL16(g, l) __builtin_amdgcn_global_load_lds( \
    (const __attribute__((address_space(1))) void*)(g), \
    (__attribute__((address_space(3))) void*)(l), 16, 0, 0)

// ---------------- prep: W [2048][128] f32 -> W^T [3*128][2048] bf16 (LDS transpose) ----------------
__global__ __launch_bounds__(256) void prep_wt(const float* __restrict__ Wq,
                                               const float* __restrict__ Wk,
                                               const float* __restrict__ Wv,
                                               ushort* __restrict__ wt){
    __shared__ float ld[64][129];
    const int w  = blockIdx.y;
    const int k0 = blockIdx.x * 64;
    const int tid = threadIdx.x;
    const float* W = (w == 0) ? Wq : ((w == 1) ? Wk : Wv);
    #pragma unroll
    for (int ii = 0; ii < 32; ii++){
        int idx = tid + 256 * ii;
        int row = idx >> 7, col = idx & 127;
        ld[row][col] = W[(size_t)(k0 + row) * HEAD + col];
    }
    __syncthreads();
    int n  = tid >> 1;
    int kh = (tid & 1) * 32;
    __attribute__((aligned(16))) ushort tmp[32];
    #pragma unroll
    for (int ii = 0; ii < 32; ii++) tmp[ii] = f2bf(ld[kh + ii][n]);
    ushort* dst = wt + (size_t)(w * HEAD + n) * EMBED + k0 + kh;
    #pragma unroll
    for (int q = 0; q < 4; q++)
        *(short8*)(dst + q * 8) = *(const short8*)(tmp + q * 8);
}

// ---------------- Fused QKV GEMM: [16384 x 2048] x [2048 x 384] ----------------
// BM=64, BN=192 (n-split x2), BK=64, 4 waves (wave tile 64m x 48n). Grid (2, 256) = 512 blocks.
// x: reg-staged f32->bf16 into padded LDS; W: global_load_lds (linear dest, XOR-swizzled src).
__global__ __launch_bounds__(256) void qkv_gemm(const float* __restrict__ x,
                                                const ushort* __restrict__ wt,
                                                const float* __restrict__ bq,
                                                const float* __restrict__ bk,
                                                const float* __restrict__ bv,
                                                ushort* __restrict__ Qb,
                                                ushort* __restrict__ Kb,
                                                ushort* __restrict__ Vt){
    __shared__ char smem[67584];
    // layout: xsb(buf i) = smem + i*9216               [64][144B] padded
    //         wlb(buf i) = smem + 18432 + i*24576      [192][128B] linear, chunk-swizzled
    float* ts = (float*)smem;                           // epilogue V transpose [64][132] f32

    const int half  = blockIdx.x;
    const int mtile = blockIdx.y;
    const int tid   = threadIdx.x;
    const int lane  = tid & 63;
    const int wid   = tid >> 6;
    const int l15   = lane & 15, lhi = lane >> 4;
    const int xrow0 = mtile * 64;

    const int srow = tid >> 3;      // 0..31 (x stage row, +32 for 2nd chunk)
    const int ssub = tid & 7;       // 8-f32 chunk within row

    const ushort* wsrc_base = wt + (size_t)(half * 192) * EMBED;
    const int grow = (lane >> 3);   // gll: row within 8-row group
    const int gch  = lane & 7;      // gll: 16B chunk

    f32x4 acc[4][3];
    #pragma unroll
    for (int i = 0; i < 4; i++)
        #pragma unroll
        for (int j = 0; j < 3; j++) acc[i][j] = (f32x4){0.f,0.f,0.f,0.f};

    float4 xr[2][2];
    // ---- prologue: stage kt=0 ----
    {
        const float* xp = x + (size_t)xrow0 * EMBED;
        #pragma unroll
        for (int h = 0; h < 2; h++){
            xr[h][0] = *(const float4*)(xp + (size_t)(srow + 32*h) * EMBED + ssub * 8);
            xr[h][1] = *(const float4*)(xp + (size_t)(srow + 32*h) * EMBED + ssub * 8 + 4);
        }
        const ushort* wsrc = wsrc_base;
        #pragma unroll
        for (int i = 0; i < 6; i++){
            int r0  = wid * 48 + i * 8;
            int row = r0 + grow;
            GLL16(wsrc + (size_t)row * EMBED + ((gch ^ (row & 7)) * 8), smem + 18432 + r0 * 128);
        }
        #pragma unroll
        for (int h = 0; h < 2; h++){
            __attribute__((aligned(16))) ushort t8[8];
            t8[0]=f2bf(xr[h][0].x); t8[1]=f2bf(xr[h][0].y); t8[2]=f2bf(xr[h][0].z); t8[3]=f2bf(xr[h][0].w);
            t8[4]=f2bf(xr[h][1].x); t8[5]=f2bf(xr[h][1].y); t8[6]=f2bf(xr[h][1].z); t8[7]=f2bf(xr[h][1].w);
            *(short8*)(smem + (srow + 32*h) * 144 + ssub * 16) = *(const short8*)t8;
        }
    }
    __syncthreads();

    int cur = 0;
    for (int kt = 0; kt < EMBED / 64; ++kt){
        char* xsb_c = smem + cur * 9216;
        char* wlb_c = smem + 18432 + cur * 24576;
        char* xsb_n = smem + (cur ^ 1) * 9216;
        char* wlb_n = smem + 18432 + (cur ^ 1) * 24576;
        // issue next-tile loads early (hide HBM latency under MFMA)
        if (kt < EMBED / 64 - 1){
            const float* xp = x + (size_t)xrow0 * EMBED + (kt + 1) * 64;
            #pragma unroll
            for (int h = 0; h < 2; h++){
                xr[h][0] = *(const float4*)(xp + (size_t)(srow + 32*h) * EMBED + ssub * 8);
                xr[h][1] = *(const float4*)(xp + (size_t)(srow + 32*h) * EMBED + ssub * 8 + 4);
            }
            const ushort* wsrc = wsrc_base + (kt + 1) * 64;
            #pragma unroll
            for (int i = 0; i < 6; i++){
                int r0  = wid * 48 + i * 8;
                int row = r0 + grow;
                GLL16(wsrc + (size_t)row * EMBED + ((gch ^ (row & 7)) * 8), wlb_n + r0 * 128);
            }
        }
        // compute from current buffer
        #pragma unroll
        for (int kc = 0; kc < 2; kc++){
            bf16x8 af[4], bfj[3];
            #pragma unroll
            for (int i = 0; i < 4; i++)
                af[i] = *(const bf16x8*)(xsb_c + (i*16 + l15) * 144 + kc*64 + lhi*16);
            #pragma unroll
            for (int j = 0; j < 3; j++){
                int row = wid * 48 + j * 16 + l15;
                bfj[j] = *(const bf16x8*)(wlb_c + row * 128 + (((kc*4 + lhi) ^ (l15 & 7)) * 16));
            }
            #pragma unroll
            for (int i = 0; i < 4; i++)
                #pragma unroll
                for (int j = 0; j < 3; j++)
                    acc[i][j] = MFMA16(af[i], bfj[j], acc[i][j]);
        }
        // write staged x into next buffer
        if (kt < EMBED / 64 - 1){
            #pragma unroll
            for (int h = 0; h < 2; h++){
                __attribute__((aligned(16))) ushort t8[8];
                t8[0]=f2bf(xr[h][0].x); t8[1]=f2bf(xr[h][0].y); t8[2]=f2bf(xr[h][0].z); t8[3]=f2bf(xr[h][0].w);
                t8[4]=f2bf(xr[h][1].x); t8[5]=f2bf(xr[h][1].y); t8[6]=f2bf(xr[h][1].z); t8[7]=f2bf(xr[h][1].w);
                *(short8*)(xsb_n + (srow + 32*h) * 144 + ssub * 16) = *(const short8*)t8;
            }
        }
        __syncthreads();
        cur ^= 1;
    }

    // ---- epilogue ----
    float bval[3];
    #pragma unroll
    for (int j = 0; j < 3; j++){
        int c = half * 192 + wid * 48 + j * 16 + l15;
        bval[j] = (c < 128) ? bq[c] : ((c < 256) ? bk[c - 128] : bv[c - 256]);
    }
    #pragma unroll
    for (int j = 0; j < 3; j++){
        int cb = half * 192 + wid * 48 + j * 16;
        if (cb < 256){
            ushort* dst = (cb < 128) ? Qb : Kb;
            int cl = (cb < 128) ? (cb + l15) : (cb - 128 + l15);
            #pragma unroll
            for (int i = 0; i < 4; i++)
                #pragma unroll
                for (int r = 0; r < 4; r++)
                    dst[(size_t)(mtile*64 + i*16 + lhi*4 + r) * HEAD + cl] = f2bf(acc[i][j][r] + bval[j]);
        }
    }
    if (half == 1){
        __syncthreads();
        #pragma unroll
        for (int j = 0; j < 3; j++){
            int cb = 192 + wid * 48 + j * 16;
            if (cb >= 256){
                int vc = cb - 256 + l15;
                #pragma unroll
                for (int i = 0; i < 4; i++)
                    #pragma unroll
                    for (int r = 0; r < 4; r++)
                        ts[(i*16 + lhi*4 + r) * 132 + vc] = acc[i][j][r] + bval[j];
            }
        }
        __syncthreads();
        int n  = tid >> 1;
        int mc = (tid & 1) * 32;
        int bb = mtile >> 5;
        int trow = (mtile & 31) * 64 + mc;
        __attribute__((aligned(16))) ushort tmp[32];
        #pragma unroll
        for (int ii = 0; ii < 32; ii++) tmp[ii] = f2bf(ts[(mc + ii) * 132 + n]);
        ushort* dst = Vt + ((size_t)(bb * HEAD + n)) * SEQ + trow;
        #pragma unroll
        for (int q = 0; q < 4; q++)
            *(short8*)(dst + q * 8) = *(const short8*)(tmp + q * 8);
    }
}

// ---------------- Flash attention, causal, kv-split x2 ----------------
// Grid (64, 8): slot = blockIdx.x; qt balanced pairing; partials to po/pm/pl.
__global__ __launch_bounds__(256) void attn(const ushort* __restrict__ Qb,
                                            const ushort* __restrict__ Kb,
                                            const ushort* __restrict__ Vt,
                                            float* __restrict__ po,
                                            float* __restrict__ pm,
                                            float* __restrict__ pl){
    __shared__ char smem[40960];
    char* Ks = smem;            // [64 kv][256 B] chunk-swizzled (^row&15)
    char* Vs = smem + 16384;    // [128 d][128 B] chunk-swizzled (^d&7)
    char* Ps = smem + 32768;    // 4 waves x [16 q][128 B] chunk-swizzled (^q&7)

    const int slot = blockIdx.x;
    const int b    = blockIdx.y;
    const int qi   = slot >> 1;
    const int qt   = (b < 4) ? qi : (31 - qi);     // anti-correlated pairing: id & id+256
    const int half = slot & 1;
    const int NT   = qt + 1;
    const int tmid = (NT + 1) >> 1;
    const int t0   = half ? tmid : 0;
    const int t1   = half ? NT : tmid;

    const int qb    = qt * 64;
    const int tid   = threadIdx.x;
    const int lane  = tid & 63, wid = tid >> 6;
    const int l15   = lane & 15, lhi = lane >> 4;
    const float scale = 0.08838834764831845f;   // 1/sqrt(128)

    bf16x8 qf[4];
    {
        const ushort* qp = Qb + ((size_t)(b * SEQ + qb + wid * 16 + l15)) * HEAD;
        #pragma unroll
        for (int kc = 0; kc < 4; kc++)
            qf[kc] = *(const bf16x8*)(qp + kc * 32 + lhi * 8);
    }

    f32x4 o[8];
    #pragma unroll
    for (int d = 0; d < 8; d++) o[d] = (f32x4){0.f,0.f,0.f,0.f};
    float mr[4] = {-1e30f,-1e30f,-1e30f,-1e30f};
    float lr[4] = {0.f,0.f,0.f,0.f};

    char* Pw = Ps + wid * 2048;

    for (int t = t0; t < t1; ++t){
        const int kvb = t * 64;
        __syncthreads();
        #pragma unroll
        for (int j = 0; j < 4; j++){
            int c = tid + 256 * j;
            int row = c >> 4, ch = c & 15;
            short8 v = *(const short8*)(Kb + ((size_t)(b * SEQ + kvb + row)) * HEAD + ch * 8);
            *(short8*)(Ks + row * 256 + ((ch ^ (row & 15)) * 16)) = v;
        }
        #pragma unroll
        for (int j = 0; j < 4; j++){
            int c = tid + 256 * j;
            int d = c >> 3, ch = c & 7;
            short8 v = *(const short8*)(Vt + ((size_t)(b * HEAD + d)) * SEQ + kvb + ch * 8);
            *(short8*)(Vs + d * 128 + ((ch ^ (d & 7)) * 16)) = v;
        }
        __syncthreads();

        f32x4 s[4];
        #pragma unroll
        for (int ns = 0; ns < 4; ns++){
            s[ns] = (f32x4){0.f,0.f,0.f,0.f};
            int row = ns * 16 + l15;
            #pragma unroll
            for (int kc = 0; kc < 4; kc++){
                int ch = (kc * 4 + lhi) ^ (row & 15);
                bf16x8 bfr = *(const bf16x8*)(Ks + row * 256 + ch * 16);
                s[ns] = MFMA16(qf[kc], bfr, s[ns]);
            }
        }

        float mx[4];
        #pragma unroll
        for (int r = 0; r < 4; r++){
            #pragma unroll
            for (int ns = 0; ns < 4; ns++){
                float v = s[ns][r] * scale;
                if (t == qt){
                    int kvg = kvb + ns * 16 + l15;
                    int qg  = qb + wid * 16 + lhi * 4 + r;
                    if (kvg > qg) v = -1e30f;
                }
                s[ns][r] = v;
            }
            float m0 = fmaxf(fmaxf(s[0][r], s[1][r]), fmaxf(s[2][r], s[3][r]));
            m0 = fmaxf(m0, __shfl_xor(m0, 1));
            m0 = fmaxf(m0, __shfl_xor(m0, 2));
            m0 = fmaxf(m0, __shfl_xor(m0, 4));
            m0 = fmaxf(m0, __shfl_xor(m0, 8));
            mx[r] = m0;
        }
        float alpha[4];
        #pragma unroll
        for (int r = 0; r < 4; r++){
            float mn = fmaxf(mr[r], mx[r]);
            alpha[r] = __expf(mr[r] - mn);
            mr[r] = mn;
            float sum = 0.f;
            #pragma unroll
            for (int ns = 0; ns < 4; ns++){
                float p = __expf(s[ns][r] - mn);
                s[ns][r] = p;
                sum += p;
            }
            sum += __shfl_xor(sum, 1);
            sum += __shfl_xor(sum, 2);
            sum += __shfl_xor(sum, 4);
            sum += __shfl_xor(sum, 8);
            lr[r] = lr[r] * alpha[r] + sum;
        }
        #pragma unroll
        for (int d = 0; d < 8; d++)
            #pragma unroll
            for (int r = 0; r < 4; r++) o[d][r] *= alpha[r];

        #pragma unroll
        for (int ns = 0; ns < 4; ns++)
            #pragma unroll
            for (int r = 0; r < 4; r++){
                int row = lhi * 4 + r;
                int byteoff = row * 128 + (((ns * 16 + l15) * 2) ^ ((row & 7) << 4));
                *(ushort*)(Pw + byteoff) = f2bf(s[ns][r]);
            }
        asm volatile("s_waitcnt lgkmcnt(0)" ::: "memory");
        __builtin_amdgcn_sched_barrier(0);

        #pragma unroll
        for (int kc = 0; kc < 2; kc++){
            int abyte = l15 * 128 + ((kc * 64 + lhi * 16) ^ ((l15 & 7) << 4));
            bf16x8 af = *(const bf16x8*)(Pw + abyte);
            #pragma unroll
            for (int ds = 0; ds < 8; ds++){
                int drow = ds * 16 + l15;
                int bbyte = drow * 128 + ((kc * 64 + lhi * 16) ^ ((drow & 7) << 4));
                bf16x8 bfr = *(const bf16x8*)(Vs + bbyte);
                o[ds] = MFMA16(af, bfr, o[ds]);
            }
        }
    }

    // store partials (unnormalized o, running m, l)
    float* pob = po + ((size_t)half * 16384 + (size_t)b * SEQ) * HEAD;
    #pragma unroll
    for (int r = 0; r < 4; r++){
        int q = qb + wid * 16 + lhi * 4 + r;
        #pragma unroll
        for (int ds = 0; ds < 8; ds++)
            pob[(size_t)q * HEAD + ds * 16 + l15] = o[ds][r];
        if (l15 == 0){
            pm[half * 16384 + b * SEQ + q] = mr[r];
            pl[half * 16384 + b * SEQ + q] = lr[r];
        }
    }
}

// ---------------- merge two kv-halves ----------------
__global__ __launch_bounds__(256) void merge(const float* __restrict__ po,
                                             const float* __restrict__ pm,
                                             const float* __restrict__ pl,
                                             float* __restrict__ out){
    int g = blockIdx.x * 256 + threadIdx.x;
    int row = g >> 2;
    int dq  = (g & 3) * 32;
    float m0 = pm[row], m1 = pm[16384 + row];
    float l0 = pl[row], l1 = pl[16384 + row];
    float M  = fmaxf(m0, m1);
    float w0 = __expf(m0 - M), w1 = __expf(m1 - M);
    float inv = 1.0f / (w0 * l0 + w1 * l1);
    const float4* p0 = (const float4*)(po + (size_t)row * HEAD + dq);
    const float4* p1 = (const float4*)(po + (size_t)(16384 + row) * HEAD + dq);
    float4* op = (float4*)(out + (size_t)row * HEAD + dq);
    #pragma unroll
    for (int i = 0; i < 8; i++){
        float4 a = p0[i], c = p1[i];
        float4 r;
        r.x = (w0*a.x + w1*c.x) * inv;
        r.y = (w0*a.y + w1*c.y) * inv;
        r.z = (w0*a.z + w1*c.z) * inv;
        r.w = (w0*a.w + w1*c.w) * inv;
        op[i] = r;
    }
}

extern "C" void kernel_launch(void* const* d_in, const int* in_sizes, int n_in,
                              void* d_out, int out_size, void* d_ws, size_t ws_size,
                              hipStream_t stream){
    const float* x  = (const float*)d_in[0];
    const float* Wq = (const float*)d_in[1];
    const float* bq = (const float*)d_in[2];
    const float* Wk = (const float*)d_in[3];
    const float* bk = (const float*)d_in[4];
    const float* Wv = (const float*)d_in[5];
    const float* bv = (const float*)d_in[6];
    float* out = (float*)d_out;

    char* ws = (char*)d_ws;
    ushort* Qb = (ushort*)ws;                                  // 4 MB   [16384][128]
    ushort* Kb = (ushort*)(ws + (size_t)4  * 1024 * 1024);     // 4 MB   [16384][128]
    ushort* Vt = (ushort*)(ws + (size_t)8  * 1024 * 1024);     // 4 MB   [8][128][2048]
    ushort* Wt = (ushort*)(ws + (size_t)12 * 1024 * 1024);     // 1.57MB [384][2048]
    float*  po = (float*) (ws + (size_t)14 * 1024 * 1024);     // 16.8MB [2][16384][128]
    float*  pm = (float*) (ws + (size_t)31 * 1024 * 1024);     // 131KB  [2][16384]
    float*  pl = (float*) (ws + (size_t)31 * 1024 * 1024 + 262144);

    prep_wt <<<dim3(32, 3), 256, 0, stream>>>(Wq, Wk, Wv, Wt);
    qkv_gemm<<<dim3(2, 256), 256, 0, stream>>>(x, Wt, bq, bk, bv, Qb, Kb, Vt);
    attn    <<<dim3(64, 8), 256, 0, stream>>>(Qb, Kb, Vt, po, pm, pl);
    merge   <<<256, 256, 0, stream>>>(po, pm, pl, out);
}